// Round 4
// baseline (263.889 us; speedup 1.0000x reference)
//
#include <hip/hip_runtime.h>
#include <hip/hip_fp16.h>
#include <stdint.h>

// Problem constants (from reference setup_inputs)
#define BATCH 256
#define PSEL  128
#define IN_DIM 3200
#define O1_DIM 8192
#define O3_DIM 4096

// ---------------------------------------------------------------------------
// transpose x [256, 3200] fp32 -> xT [3200, 256] fp16
// Fused: out = -8.0 (final bias; atomics accumulate on top) and
// stats accumulators (4 x 256 floats) = 0.
// ---------------------------------------------------------------------------
__global__ __launch_bounds__(256) void transpose_kernel(const float* __restrict__ x,
                                                        __half* __restrict__ xT,
                                                        float* __restrict__ out,
                                                        float* __restrict__ stats) {
    int tx = threadIdx.x;       // 32
    int ty = threadIdx.y;       // 8
    int tid = ty * 32 + tx;
    int gid = blockIdx.y * gridDim.x + blockIdx.x;   // 0..799
    if (gid < 256) out[gid * 256 + tid] = -8.0f;
    else if (gid < 260) stats[(gid - 256) * 256 + tid] = 0.0f;

    __shared__ float tile[32][33];
    int i0 = blockIdx.x * 32;   // input-dim tile (3200/32 = 100)
    int b0 = blockIdx.y * 32;   // batch tile    (256/32 = 8)
#pragma unroll
    for (int k = 0; k < 4; ++k)
        tile[ty + k * 8][tx] = x[(size_t)(b0 + ty + k * 8) * IN_DIM + i0 + tx];
    __syncthreads();
#pragma unroll
    for (int k = 0; k < 4; ++k)
        xT[(size_t)(i0 + ty + k * 8) * BATCH + b0 + tx] =
            __float2half(tile[tx][ty + k * 8]);
}

// ---------------------------------------------------------------------------
// popcnt layer: one WAVE per output o; block = 4 waves = 4 outputs.
// Each wave gathers all 128 rows of its output: lanes 0-31 row 2i, lanes
// 32-63 row 2i+1, 16 B/lane -> 64 dwordx4 loads, no barriers in the loop.
// shfl_xor(32) merges the two halves; lanes 0-31 do the epilogue (8 b each).
// Layernorm of the INPUT folded algebraically:
//   sum_p w_p*((v-mu)*rs*g_p + be_p) = rs*acc + sumC - rs*mu*sumA
// Stats of the OUTPUT (for the next layer's LN) fused: per-block LDS
// reduction of h and h^2, then 512 atomics.
// FINAL: the block's 4 outputs share one group (o>>4); LDS-reduce then one
// atomicAdd per batch element into out (pre-init'd to -8).
// ---------------------------------------------------------------------------
template <bool NORM, bool FINAL>
__global__ __launch_bounds__(256, 8) void popcnt_kernel(
    const __half* __restrict__ actT,  // [Nin, 256] fp16, rows = 512 B
    const int* __restrict__ sel,      // [Nout, 128]
    const float* __restrict__ w,      // [Nout, 128]
    const float* __restrict__ bias,   // [Nout]
    const float* __restrict__ g,      // [Nin]  (NORM only)
    const float* __restrict__ be,     // [Nin]  (NORM only)
    const float* __restrict__ gsum,   // [256]  (NORM only) input stats
    const float* __restrict__ gsq,    // [256]  (NORM only)
    float inv_n,                      // 1/Nin  (NORM only)
    void* __restrict__ outp,          // fp16 [Nout,256], or final fp32 [256,256]
    float* __restrict__ osum,         // [256] output stats (non-FINAL)
    float* __restrict__ osq)          // [256]
{
    const int t    = threadIdx.x;     // 0..255
    const int wv   = t >> 6;          // wave 0..3 = local output
    const int lane = t & 63;
    const int half = lane >> 5;
    const int sub  = lane & 31;
    const int o    = blockIdx.x * 4 + wv;

    __shared__ alignas(16) uint32_t s_pair[4][2 * PSEL];  // {byte_offset, A_p}
    __shared__ float s_p1[4][BATCH];                      // h partials
    __shared__ float s_p2[FINAL ? 1 : 4][FINAL ? 1 : BATCH];  // h^2 partials

    // ---- prologue: each wave loads its own 128 sel/w (2 entries per lane) ----
    float sA = 0.0f, sC = 0.0f;
    {
        int e0 = o * PSEL + lane;
        int i0 = __builtin_nontemporal_load(&sel[e0]);
        int i1 = __builtin_nontemporal_load(&sel[e0 + 64]);
        float w0 = __builtin_nontemporal_load(&w[e0]);
        float w1 = __builtin_nontemporal_load(&w[e0 + 64]);
        float sw0 = 1.0f / (1.0f + __expf(-w0));   // resilu(w) == sigmoid(w)
        float sw1 = 1.0f / (1.0f + __expf(-w1));
        float a0, a1, c0, c1;
        if (NORM) {
            a0 = sw0 * g[i0]; c0 = sw0 * be[i0];
            a1 = sw1 * g[i1]; c1 = sw1 * be[i1];
        } else {
            a0 = sw0; a1 = sw1; c0 = c1 = 0.0f;
        }
        uint2* pw = (uint2*)s_pair[wv];
        uint2 p0; p0.x = (uint32_t)i0 << 9; p0.y = __float_as_uint(a0);
        uint2 p1; p1.x = (uint32_t)i1 << 9; p1.y = __float_as_uint(a1);
        pw[lane]      = p0;
        pw[lane + 64] = p1;
        if (NORM) {                      // in-wave reduction of sumA, sumC
            float va = a0 + a1, vc = c0 + c1;
#pragma unroll
            for (int off = 32; off > 0; off >>= 1) {
                va += __shfl_xor(va, off, 64);
                vc += __shfl_xor(vc, off, 64);
            }
            sA = va; sC = vc;
        }
    }
    __syncthreads();   // publish s_pair (also covers nothing else; one barrier)

    // ---- gather main loop: 64 dwordx4 per wave, 2 rows per instruction ----
    const uint2* pairs = (const uint2*)s_pair[wv];
    float acc[8] = {0.f, 0.f, 0.f, 0.f, 0.f, 0.f, 0.f, 0.f};
#pragma unroll 8
    for (int i = 0; i < 64; ++i) {
        uint2 pr = pairs[2 * i + half];               // LDS broadcast (2 addrs)
        uint4 d = *(const uint4*)((const char*)actT + pr.x + sub * 16);
        float A = __uint_as_float(pr.y);
        float2 f;
        f = __half22float2(*(const __half2*)&d.x);
        acc[0] = fmaf(A, f.x, acc[0]); acc[1] = fmaf(A, f.y, acc[1]);
        f = __half22float2(*(const __half2*)&d.y);
        acc[2] = fmaf(A, f.x, acc[2]); acc[3] = fmaf(A, f.y, acc[3]);
        f = __half22float2(*(const __half2*)&d.z);
        acc[4] = fmaf(A, f.x, acc[4]); acc[5] = fmaf(A, f.y, acc[5]);
        f = __half22float2(*(const __half2*)&d.w);
        acc[6] = fmaf(A, f.x, acc[6]); acc[7] = fmaf(A, f.y, acc[7]);
    }

    // merge the two 32-row halves within the wave
#pragma unroll
    for (int j = 0; j < 8; ++j) acc[j] += __shfl_xor(acc[j], 32, 64);

    // ---- epilogue: lanes 0-31 hold 8 batch elements each ----
    if (lane < 32) {
        float bo = bias[o];
        float h[8];
        if (NORM) {
            float4 m0 = ((const float4*)gsum)[2 * sub];
            float4 m1 = ((const float4*)gsum)[2 * sub + 1];
            float4 q0 = ((const float4*)gsq)[2 * sub];
            float4 q1 = ((const float4*)gsq)[2 * sub + 1];
            float ms[8] = {m0.x, m0.y, m0.z, m0.w, m1.x, m1.y, m1.z, m1.w};
            float qs[8] = {q0.x, q0.y, q0.z, q0.w, q1.x, q1.y, q1.z, q1.w};
#pragma unroll
            for (int j = 0; j < 8; ++j) {
                float m  = ms[j] * inv_n;
                float q  = qs[j] * inv_n;
                float rs = rsqrtf(q - m * m + 1e-12f);
                float z  = rs * acc[j] + sC - rs * m * sA - bo;
                h[j] = 1.0f / (1.0f + __expf(-z));
            }
        } else {
#pragma unroll
            for (int j = 0; j < 8; ++j)
                h[j] = 1.0f / (1.0f + __expf(-(acc[j] - bo)));
        }

        if (!FINAL) {
            __half2 h01 = __floats2half2_rn(h[0], h[1]);
            __half2 h23 = __floats2half2_rn(h[2], h[3]);
            __half2 h45 = __floats2half2_rn(h[4], h[5]);
            __half2 h67 = __floats2half2_rn(h[6], h[7]);
            uint4 st;
            st.x = *(uint32_t*)&h01; st.y = *(uint32_t*)&h23;
            st.z = *(uint32_t*)&h45; st.w = *(uint32_t*)&h67;
            *(uint4*)((__half*)outp + (size_t)o * BATCH + sub * 8) = st;
        }
#pragma unroll
        for (int j = 0; j < 8; ++j) {
            s_p1[wv][8 * sub + j] = h[j];
            if (!FINAL) s_p2[wv][8 * sub + j] = h[j] * h[j];
        }
    }
    __syncthreads();

    // ---- block-level reduction of the 4 outputs' h (and h^2) ----
    if (t < BATCH) {
        float v = s_p1[0][t] + s_p1[1][t] + s_p1[2][t] + s_p1[3][t];
        if (FINAL) {
            // all 4 outputs of this block are in group blockIdx.x>>2
            atomicAdd(&((float*)outp)[t * 256 + (blockIdx.x >> 2)], v);
        } else {
            atomicAdd(&osum[t], v);
            float q = s_p2[0][t] + s_p2[1][t] + s_p2[2][t] + s_p2[3][t];
            atomicAdd(&osq[t], q);
        }
    }
}

// ---------------------------------------------------------------------------
extern "C" void kernel_launch(void* const* d_in, const int* in_sizes, int n_in,
                              void* d_out, int out_size, void* d_ws, size_t ws_size,
                              hipStream_t stream) {
    const float* x    = (const float*)d_in[0];
    const int*   sel1 = (const int*)d_in[1];
    const float* w1   = (const float*)d_in[2];
    const float* b1   = (const float*)d_in[3];
    const float* g1   = (const float*)d_in[4];
    const float* be1  = (const float*)d_in[5];
    const int*   sel2 = (const int*)d_in[6];
    const float* w2   = (const float*)d_in[7];
    const float* b2   = (const float*)d_in[8];
    const float* g2   = (const float*)d_in[9];
    const float* be2  = (const float*)d_in[10];
    const int*   sel3 = (const int*)d_in[11];
    const float* w3   = (const float*)d_in[12];
    const float* b3   = (const float*)d_in[13];
    float* out = (float*)d_out;

    // workspace layout (fp16 activations)
    char* ws = (char*)d_ws;
    __half* xT  = (__half*)(ws);                          // 3200*256*2 = 1,638,400
    __half* h1T = (__half*)(ws + 1638400);                // 8192*256*2 = 4,194,304
    __half* h2T = (__half*)(ws + 1638400 + 4194304);      // 4,194,304
    float* stats = (float*)(ws + 1638400 + 2 * 4194304);  // 4 * 256 floats
    float* gs1 = stats;
    float* gq1 = stats + 256;
    float* gs2 = stats + 512;
    float* gq2 = stats + 768;

    // transpose + init(out, stats) fused
    transpose_kernel<<<dim3(IN_DIM / 32, BATCH / 32), dim3(32, 8), 0, stream>>>(
        x, xT, out, stats);

    // Layer 1: x -> h1 (no input norm); emits stats of h1
    popcnt_kernel<false, false><<<O1_DIM / 4, 256, 0, stream>>>(
        xT, sel1, w1, b1, nullptr, nullptr, nullptr, nullptr, 0.0f,
        h1T, gs1, gq1);

    // Layer 2: layernorm(h1) folded in; emits stats of h2
    popcnt_kernel<true, false><<<O1_DIM / 4, 256, 0, stream>>>(
        h1T, sel2, w2, b2, g1, be1, gs1, gq1, 1.0f / (float)O1_DIM,
        h2T, gs2, gq2);

    // Layer 3: layernorm(h2) folded in; final group-sum into out
    popcnt_kernel<true, true><<<O3_DIM / 4, 256, 0, stream>>>(
        h2T, sel3, w3, b3, g2, be2, gs2, gq2, 1.0f / (float)O1_DIM,
        out, nullptr, nullptr);
}

// Round 5
// 235.081 us; speedup vs baseline: 1.1225x; 1.1225x over previous
//
#include <hip/hip_runtime.h>
#include <hip/hip_fp16.h>
#include <stdint.h>

// Problem constants (from reference setup_inputs)
#define BATCH 256
#define PSEL  128
#define IN_DIM 3200
#define O1_DIM 8192
#define O3_DIM 4096

// ---------------------------------------------------------------------------
// transpose x [256, 3200] fp32 -> xT [3200, 256] fp16
// Fused: out = -8.0 (final bias; atomics accumulate on top) and
// stats accumulators (4 x 256 floats) = 0.
// ---------------------------------------------------------------------------
__global__ __launch_bounds__(256) void transpose_kernel(const float* __restrict__ x,
                                                        __half* __restrict__ xT,
                                                        float* __restrict__ out,
                                                        float* __restrict__ stats) {
    int tx = threadIdx.x;       // 32
    int ty = threadIdx.y;       // 8
    int tid = ty * 32 + tx;
    int gid = blockIdx.y * gridDim.x + blockIdx.x;   // 0..799
    if (gid < 256) out[gid * 256 + tid] = -8.0f;
    else if (gid < 260) stats[(gid - 256) * 256 + tid] = 0.0f;

    __shared__ float tile[32][33];
    int i0 = blockIdx.x * 32;   // input-dim tile (3200/32 = 100)
    int b0 = blockIdx.y * 32;   // batch tile    (256/32 = 8)
#pragma unroll
    for (int k = 0; k < 4; ++k)
        tile[ty + k * 8][tx] = x[(size_t)(b0 + ty + k * 8) * IN_DIM + i0 + tx];
    __syncthreads();
#pragma unroll
    for (int k = 0; k < 4; ++k)
        xT[(size_t)(i0 + ty + k * 8) * BATCH + b0 + tx] =
            __float2half(tile[tx][ty + k * 8]);
}

// ---------------------------------------------------------------------------
// stats: per-batch-column sum and sum-of-squares of hT [N, 256] (fp16 in, fp32 acc)
// grid = 256 blocks, each handles N/256 contiguous rows; coalesced reads.
// ---------------------------------------------------------------------------
__global__ __launch_bounds__(256) void stats_kernel(const __half* __restrict__ hT,
                                                    float* __restrict__ gsum,
                                                    float* __restrict__ gsq,
                                                    int rows_per_block) {
    int t = threadIdx.x;
    const __half* p = hT + (size_t)blockIdx.x * rows_per_block * BATCH + t;
    float s = 0.0f, q = 0.0f;
    for (int r = 0; r < rows_per_block; ++r) {
        float v = __half2float(p[(size_t)r * BATCH]);
        s += v;
        q = fmaf(v, v, q);
    }
    atomicAdd(&gsum[t], s);
    atomicAdd(&gsq[t], q);
}

// ---------------------------------------------------------------------------
// popcnt layer: one block (256 threads) per output o.
// Thread t: batch-dword col = t&127 (batch elems 2col,2col+1), row-parity
// rp = t>>7. Each thread issues 64 thin dword loads (rows 2i+rp), which are
// 256 B coalesced per wave and tolerate low VGPR counts (1 reg per in-flight
// load) -> high per-CU MLP at high occupancy. Halves combined via LDS.
// Layernorm of the INPUT folded algebraically:
//   sum_p w_p*((v-mu)*rs*g_p + be_p) = rs*acc + sumC - rs*mu*sumA
// FINAL: atomicAdd sigmoid into out[b*256 + o/16] (pre-init'd to -8).
// ---------------------------------------------------------------------------
template <bool NORM, bool FINAL>
__global__ __launch_bounds__(256) void popcnt_kernel(
    const __half* __restrict__ actT,  // [Nin, 256] fp16, rows = 512 B
    const int* __restrict__ sel,      // [Nout, 128]
    const float* __restrict__ w,      // [Nout, 128]
    const float* __restrict__ bias,   // [Nout]
    const float* __restrict__ g,      // [Nin]  (NORM only)
    const float* __restrict__ be,     // [Nin]  (NORM only)
    const float* __restrict__ gsum,   // [256]  (NORM only)
    const float* __restrict__ gsq,    // [256]  (NORM only)
    float inv_n,                      // 1/Nin  (NORM only)
    void* __restrict__ outp)          // fp16 [Nout,256] or final fp32 [256,256]
{
    const int o   = blockIdx.x;
    const int t   = threadIdx.x;      // 0..255
    const int col = t & 127;          // batch dword
    const int rp  = t >> 7;           // row parity

    __shared__ alignas(16) uint32_t s_pair[2 * PSEL];  // {byte_offset, A_p}
    __shared__ float s_rA[PSEL], s_rC[PSEL];
    __shared__ float s_red[2][PSEL];
    __shared__ float s_sums[2];

    if (t < PSEL) {
        int idx  = __builtin_nontemporal_load(&sel[o * PSEL + t]);
        float ww = __builtin_nontemporal_load(&w[o * PSEL + t]);
        float sw = 1.0f / (1.0f + __expf(-ww));   // resilu(w) == sigmoid(w)
        float a, c;
        if (NORM) { a = sw * g[idx]; c = sw * be[idx]; }
        else      { a = sw;          c = 0.0f; }
        s_pair[2 * t]     = (uint32_t)idx << 9;   // idx * 256 halves * 2 B
        s_pair[2 * t + 1] = __float_as_uint(a);
        if (NORM) { s_rA[t] = a; s_rC[t] = c; }
    }
    __syncthreads();

    if (NORM && t < 64) {             // wave 0 reduces sumA, sumC over 128 entries
        float va = s_rA[t] + s_rA[t + 64];
        float vc = s_rC[t] + s_rC[t + 64];
#pragma unroll
        for (int off = 32; off > 0; off >>= 1) {
            va += __shfl_down(va, off, 64);
            vc += __shfl_down(vc, off, 64);
        }
        if (t == 0) { s_sums[0] = va; s_sums[1] = vc; }
    }

    // ---- gather: 64 thin dword loads per thread, rows 2i+rp ----
    const uint2* pairs = (const uint2*)s_pair;
    const char* base = (const char*)actT + (uint32_t)(col * 4);
    float acc0 = 0.0f, acc1 = 0.0f;
#pragma unroll 16
    for (int i = 0; i < 64; ++i) {
        uint2 pr = pairs[2 * i + rp];               // LDS broadcast per wave
        uint32_t d = *(const uint32_t*)(base + pr.x);
        float A = __uint_as_float(pr.y);
        float2 f = __half22float2(*(const __half2*)&d);
        acc0 = fmaf(A, f.x, acc0);
        acc1 = fmaf(A, f.y, acc1);
    }

    if (t >= 128) { s_red[0][col] = acc0; s_red[1][col] = acc1; }
    __syncthreads();   // also publishes s_sums

    if (t < 128) {
        acc0 += s_red[0][col];
        acc1 += s_red[1][col];

        float z0, z1;
        float bo = bias[o];
        if (NORM) {
            float2 ms = ((const float2*)gsum)[col];
            float2 qs = ((const float2*)gsq)[col];
            float m0 = ms.x * inv_n, m1 = ms.y * inv_n;
            float q0 = qs.x * inv_n, q1 = qs.y * inv_n;
            float rs0 = rsqrtf(q0 - m0 * m0 + 1e-12f);
            float rs1 = rsqrtf(q1 - m1 * m1 + 1e-12f);
            float sA = s_sums[0], sC = s_sums[1];
            z0 = rs0 * acc0 + sC - rs0 * m0 * sA - bo;
            z1 = rs1 * acc1 + sC - rs1 * m1 * sA - bo;
        } else {
            z0 = acc0 - bo;
            z1 = acc1 - bo;
        }
        float h0 = 1.0f / (1.0f + __expf(-z0));
        float h1 = 1.0f / (1.0f + __expf(-z1));

        if (FINAL) {
            float* out = (float*)outp;
            int grp = o >> 4;
            atomicAdd(&out[(2 * col) * 256 + grp], h0);
            atomicAdd(&out[(2 * col + 1) * 256 + grp], h1);
        } else {
            __half2 hv = __floats2half2_rn(h0, h1);
            *(__half2*)((__half*)outp + (size_t)o * BATCH + 2 * col) = hv;
        }
    }
}

// ---------------------------------------------------------------------------
extern "C" void kernel_launch(void* const* d_in, const int* in_sizes, int n_in,
                              void* d_out, int out_size, void* d_ws, size_t ws_size,
                              hipStream_t stream) {
    const float* x    = (const float*)d_in[0];
    const int*   sel1 = (const int*)d_in[1];
    const float* w1   = (const float*)d_in[2];
    const float* b1   = (const float*)d_in[3];
    const float* g1   = (const float*)d_in[4];
    const float* be1  = (const float*)d_in[5];
    const int*   sel2 = (const int*)d_in[6];
    const float* w2   = (const float*)d_in[7];
    const float* b2   = (const float*)d_in[8];
    const float* g2   = (const float*)d_in[9];
    const float* be2  = (const float*)d_in[10];
    const int*   sel3 = (const int*)d_in[11];
    const float* w3   = (const float*)d_in[12];
    const float* b3   = (const float*)d_in[13];
    float* out = (float*)d_out;

    // workspace layout (fp16 activations)
    char* ws = (char*)d_ws;
    __half* xT  = (__half*)(ws);                          // 3200*256*2 = 1,638,400
    __half* h1T = (__half*)(ws + 1638400);                // 8192*256*2 = 4,194,304
    __half* h2T = (__half*)(ws + 1638400 + 4194304);      // 4,194,304
    float* stats = (float*)(ws + 1638400 + 2 * 4194304);  // 4 * 256 floats
    float* gs1 = stats;
    float* gq1 = stats + 256;
    float* gs2 = stats + 512;
    float* gq2 = stats + 768;

    // transpose + init(out, stats) fused
    transpose_kernel<<<dim3(IN_DIM / 32, BATCH / 32), dim3(32, 8), 0, stream>>>(
        x, xT, out, stats);

    // Layer 1: x -> h1 (no input norm)
    popcnt_kernel<false, false><<<O1_DIM, 256, 0, stream>>>(
        xT, sel1, w1, b1, nullptr, nullptr, nullptr, nullptr, 0.0f, h1T);

    // stats of h1 for layernorm 1
    stats_kernel<<<256, 256, 0, stream>>>(h1T, gs1, gq1, O1_DIM / 256);

    // Layer 2: layernorm(h1) folded in
    popcnt_kernel<true, false><<<O1_DIM, 256, 0, stream>>>(
        h1T, sel2, w2, b2, g1, be1, gs1, gq1, 1.0f / (float)O1_DIM, h2T);

    // stats of h2 for layernorm 2
    stats_kernel<<<256, 256, 0, stream>>>(h2T, gs2, gq2, O1_DIM / 256);

    // Layer 3: layernorm(h2) folded in, final group-sum via atomics into out
    popcnt_kernel<true, true><<<O3_DIM, 256, 0, stream>>>(
        h2T, sel3, w3, b3, g2, be2, gs2, gq2, 1.0f / (float)O1_DIM, out);
}